// Round 1
// baseline (547.059 us; speedup 1.0000x reference)
//
#include <hip/hip_runtime.h>
#include <stdint.h>

#define DIN 1024
#define TLEN 2048

typedef __attribute__((ext_vector_type(8))) short bf16x8;
typedef __attribute__((ext_vector_type(4))) float f32x4;
typedef __attribute__((ext_vector_type(2))) float f32x2;

__device__ __forceinline__ short f2bf_trunc(float f) {
  union { float f; uint32_t u; } v; v.f = f;
  return (short)(v.u >> 16);
}
__device__ __forceinline__ short f2bf_rne(float f) {
  union { float f; uint32_t u; } v; v.f = f;
  uint32_t r = v.u + 0x7FFFu + ((v.u >> 16) & 1u);
  return (short)(r >> 16);
}
__device__ __forceinline__ float softplus_f(float v) {
  float e = __builtin_amdgcn_exp2f(v * 1.44269504f);
  float sp = __builtin_amdgcn_logf(1.0f + e) * 0.6931471806f;
  return v > 15.0f ? v : sp;
}
__device__ __forceinline__ void gl_lds16(const void* g, void* l) {
  __builtin_amdgcn_global_load_lds(
      (const __attribute__((address_space(1))) uint32_t*)g,
      (__attribute__((address_space(3))) uint32_t*)l, 16, 0, 0);
}
__device__ __forceinline__ f32x4 mfma16(bf16x8 a, bf16x8 b, f32x4 c) {
  return __builtin_amdgcn_mfma_f32_16x16x32_bf16(a, b, c, 0, 0, 0);
}

// ---------------- prep: weight conversions + A*log2e ----------------
__global__ void k_prep(const float* __restrict__ Wxp, const float* __restrict__ Wdt,
                       const float* __restrict__ logA,
                       short* __restrict__ wxp_bf, short* __restrict__ wdt_bf,
                       float* __restrict__ al2) {
  int i = blockIdx.x * 256 + threadIdx.x;
  if (i < 96 * 1024) wxp_bf[i] = f2bf_rne(Wxp[i]);
  if (i < 1024 * 64) wdt_bf[i] = f2bf_rne(Wdt[i]);
  if (i < 1024 * 16) al2[i] = -__expf(logA[i]) * 1.44269504f;
}

// ---------------- proj: xp = x @ Wxp^T  (MFMA bf16) ----------------
// block: 256 thr = 4 waves, 64 rows x 96 cols. wave w: rows 16w..16w+16, 6 N-tiles.
__global__ __launch_bounds__(256) void k_proj(
    const float* __restrict__ x, const short* __restrict__ wxp_bf,
    short* __restrict__ xp_dt, float* __restrict__ BC) {
  const int w = threadIdx.x >> 6;
  const int l = threadIdx.x & 63;
  const int cl = l & 15;
  const int q = l >> 4;
  const int kb = q * 8;
  const int row = blockIdx.x * 64 + w * 16 + cl;

  f32x4 acc[6];
#pragma unroll
  for (int t = 0; t < 6; ++t) acc[t] = (f32x4){0.f, 0.f, 0.f, 0.f};

  const float* xr = x + (size_t)row * DIN + kb;
#pragma unroll 2
  for (int k0 = 0; k0 < DIN; k0 += 32) {
    float4 p0 = *(const float4*)(xr + k0);
    float4 p1 = *(const float4*)(xr + k0 + 4);
    bf16x8 a;
    a[0] = f2bf_trunc(p0.x); a[1] = f2bf_trunc(p0.y);
    a[2] = f2bf_trunc(p0.z); a[3] = f2bf_trunc(p0.w);
    a[4] = f2bf_trunc(p1.x); a[5] = f2bf_trunc(p1.y);
    a[6] = f2bf_trunc(p1.z); a[7] = f2bf_trunc(p1.w);
#pragma unroll
    for (int t = 0; t < 6; ++t) {
      bf16x8 bb = *(const bf16x8*)(wxp_bf + (size_t)(t * 16 + cl) * DIN + k0 + kb);
      acc[t] = mfma16(a, bb, acc[t]);
    }
  }
  const int rbase = blockIdx.x * 64 + w * 16 + q * 4;
#pragma unroll
  for (int t = 0; t < 4; ++t)
#pragma unroll
    for (int i = 0; i < 4; ++i)
      xp_dt[(size_t)(rbase + i) * 64 + t * 16 + cl] = f2bf_trunc(acc[t][i]);
#pragma unroll
  for (int t = 4; t < 6; ++t)
#pragma unroll
    for (int i = 0; i < 4; ++i)
      BC[(size_t)(rbase + i) * 32 + (t - 4) * 16 + cl] = acc[t][i];
}

// ---------------- scan: fused dt-GEMM + selective scan ----------------
// grid 256: b = blk>>5, d0 = (blk&31)*32. 256 thr: 32 channels x 8 lanes (2 states/lane).
__global__ __launch_bounds__(256) void k_scan(
    const float* __restrict__ x, const float* __restrict__ BC,
    const short* __restrict__ xp_dt, const short* __restrict__ wdt_bf,
    const float* __restrict__ bdt, const float* __restrict__ al2,
    const float* __restrict__ Dparam, const unsigned char* __restrict__ pad,
    float* __restrict__ Y) {
  __shared__ float x_w[2][64 * 32];
  __shared__ float bc_w[2][64 * 32];
  __shared__ float dt_w[2][64 * 33];   // +1 pad: avoid write conflicts
  __shared__ float mk_w[2][64];

  const int tid = threadIdx.x;
  const int w = tid >> 6;
  const int l = tid & 63;
  const int b = blockIdx.x >> 5;
  const int d0 = (blockIdx.x & 31) * 32;
  const int grp = tid >> 3;        // channel within block (0..31)
  const int n0 = (tid & 7) * 2;    // state pair
  const int d = d0 + grp;

  const float cA0 = al2[d * 16 + n0];
  const float cA1 = al2[d * 16 + n0 + 1];
  const float Dp = Dparam[d];

  const int cl = l & 15;
  const int q = l >> 4;
  const int kb = q * 8;

  // hoisted Wdt B-fragments (2 col-tiles x 2 k-steps) + biases
  bf16x8 bw00 = *(const bf16x8*)(wdt_bf + (size_t)(d0 + cl) * 64 + kb);
  bf16x8 bw01 = *(const bf16x8*)(wdt_bf + (size_t)(d0 + cl) * 64 + 32 + kb);
  bf16x8 bw10 = *(const bf16x8*)(wdt_bf + (size_t)(d0 + 16 + cl) * 64 + kb);
  bf16x8 bw11 = *(const bf16x8*)(wdt_bf + (size_t)(d0 + 16 + cl) * 64 + 32 + kb);
  const float bias0 = bdt[d0 + cl];
  const float bias1 = bdt[d0 + 16 + cl];

  float h0 = 0.f, h1 = 0.f;

  auto stage = [&](int t0, int buf) {
    // x window: 64 x 32 floats; flat = r*1024 + w*256 + l*4 -> tt=flat>>5, cc=flat&31
    const float* xg = x + ((size_t)(b * TLEN + t0)) * DIN + d0;
#pragma unroll
    for (int r = 0; r < 2; ++r) {
      int flat = r * 1024 + w * 256 + l * 4;
      int tt = flat >> 5, cc = flat & 31;
      gl_lds16(xg + (size_t)tt * DIN + cc, &x_w[buf][r * 1024 + w * 256]);
    }
    // BC window: contiguous 2048 floats
    const float* bg = BC + ((size_t)(b * TLEN + t0)) * 32;
#pragma unroll
    for (int r = 0; r < 2; ++r) {
      int flat = r * 1024 + w * 256 + l * 4;
      gl_lds16(bg + flat, &bc_w[buf][r * 1024 + w * 256]);
    }
    if (tid < 64) mk_w[buf][tid] = pad[b * TLEN + t0 + tid] ? 0.f : 1.f;
  };

  auto dtc = [&](int t0, int buf) {
    // dt tile [64 t][32 c] = softplus(xp64 @ Wdt^T + b); wave w does rows 16w..16w+16
    const short* ag = xp_dt + ((size_t)(b * TLEN + t0 + w * 16 + cl)) * 64 + kb;
    bf16x8 a0 = *(const bf16x8*)(ag);
    bf16x8 a1 = *(const bf16x8*)(ag + 32);
    f32x4 ac0 = {0.f, 0.f, 0.f, 0.f};
    f32x4 ac1 = {0.f, 0.f, 0.f, 0.f};
    ac0 = mfma16(a0, bw00, ac0);
    ac0 = mfma16(a1, bw01, ac0);
    ac1 = mfma16(a0, bw10, ac1);
    ac1 = mfma16(a1, bw11, ac1);
#pragma unroll
    for (int i = 0; i < 4; ++i) {
      int rowo = (w * 16 + q * 4 + i) * 33;
      dt_w[buf][rowo + cl] = softplus_f(ac0[i] + bias0);
      dt_w[buf][rowo + 16 + cl] = softplus_f(ac1[i] + bias1);
    }
  };

  stage(0, 0);
  dtc(0, 0);
  __syncthreads();

  for (int win = 0; win < 32; ++win) {
    const int cur = win & 1;
    const int t0 = win * 64;
    if (win < 31) { stage(t0 + 64, cur ^ 1); dtc(t0 + 64, cur ^ 1); }

    float* yrow = Y + ((size_t)(b * TLEN + t0)) * DIN + d;
#pragma unroll 4
    for (int tt = 0; tt < 64; ++tt) {
      float dtv = dt_w[cur][tt * 33 + grp];
      float xv = x_w[cur][tt * 32 + grp];
      f32x2 Bv = *(const f32x2*)&bc_w[cur][tt * 32 + n0];
      f32x2 Cv = *(const f32x2*)&bc_w[cur][tt * 32 + 16 + n0];
      float m = mk_w[cur][tt];
      float e0 = __builtin_amdgcn_exp2f(cA0 * dtv) * m;
      float e1 = __builtin_amdgcn_exp2f(cA1 * dtv) * m;
      float dtxm = dtv * xv * m;
      h0 = fmaf(e0, h0, dtxm * Bv[0]);
      h1 = fmaf(e1, h1, dtxm * Bv[1]);
      float p = fmaf(h1, Cv[1], h0 * Cv[0]);
      p += __shfl_xor(p, 1);
      p += __shfl_xor(p, 2);
      p += __shfl_xor(p, 4);
      float yv = fmaf(Dp, xv * m, p);
      if ((tid & 7) == 0) yrow[(size_t)tt * DIN] = yv;
    }
    __syncthreads();
  }
}

extern "C" void kernel_launch(void* const* d_in, const int* in_sizes, int n_in,
                              void* d_out, int out_size, void* d_ws, size_t ws_size,
                              hipStream_t stream) {
  const float* x = (const float*)d_in[0];
  const unsigned char* pad = (const unsigned char*)d_in[1];
  const float* Wxp = (const float*)d_in[2];
  const float* Wdt = (const float*)d_in[3];
  const float* bdt = (const float*)d_in[4];
  const float* logA = (const float*)d_in[5];
  const float* Dpar = (const float*)d_in[6];
  float* Y = (float*)d_out;

  char* ws = (char*)d_ws;
  short* wxp_bf = (short*)(ws);                 // 96*1024*2   = 196608
  short* wdt_bf = (short*)(ws + 196608);        // 1024*64*2   = 131072
  float* al2    = (float*)(ws + 327680);        // 1024*16*4   = 65536
  short* xp_dt  = (short*)(ws + 393216);        // 16384*64*2  = 2097152
  float* BC     = (float*)(ws + 2490368);       // 16384*32*4  = 2097152

  hipLaunchKernelGGL(k_prep, dim3(384), dim3(256), 0, stream,
                     Wxp, Wdt, logA, wxp_bf, wdt_bf, al2);
  hipLaunchKernelGGL(k_proj, dim3(256), dim3(256), 0, stream,
                     x, wxp_bf, xp_dt, BC);
  hipLaunchKernelGGL(k_scan, dim3(256), dim3(256), 0, stream,
                     x, BC, xp_dt, wdt_bf, bdt, al2, Dpar, pad, Y);
}

// Round 2
// 398.800 us; speedup vs baseline: 1.3718x; 1.3718x over previous
//
#include <hip/hip_runtime.h>
#include <stdint.h>

#define DIN 1024
#define TLEN 2048

typedef __attribute__((ext_vector_type(8))) short bf16x8;
typedef __attribute__((ext_vector_type(4))) float f32x4;
typedef __attribute__((ext_vector_type(2))) float f32x2;

__device__ __forceinline__ short f2bf_trunc(float f) {
  union { float f; uint32_t u; } v; v.f = f;
  return (short)(v.u >> 16);
}
__device__ __forceinline__ short f2bf_rne(float f) {
  union { float f; uint32_t u; } v; v.f = f;
  uint32_t r = v.u + 0x7FFFu + ((v.u >> 16) & 1u);
  return (short)(r >> 16);
}
__device__ __forceinline__ float bf2f(short s) {
  union { uint32_t u; float f; } v; v.u = ((uint32_t)(unsigned short)s) << 16;
  return v.f;
}
__device__ __forceinline__ float softplus_f(float v) {
  float e = __builtin_amdgcn_exp2f(v * 1.44269504f);
  float sp = __builtin_amdgcn_logf(1.0f + e) * 0.6931471806f;
  return v > 15.0f ? v : sp;
}
__device__ __forceinline__ void gl_lds16(const void* g, void* l) {
  __builtin_amdgcn_global_load_lds(
      (const __attribute__((address_space(1))) uint32_t*)g,
      (__attribute__((address_space(3))) uint32_t*)l, 16, 0, 0);
}
__device__ __forceinline__ f32x4 mfma16(bf16x8 a, bf16x8 b, f32x4 c) {
  return __builtin_amdgcn_mfma_f32_16x16x32_bf16(a, b, c, 0, 0, 0);
}
// full-rate VALU cross-lane add within aligned 8-lane group
template <int CTRL>
__device__ __forceinline__ float dpp_add(float v) {
  int r = __builtin_amdgcn_update_dpp(0, __builtin_bit_cast(int, v), CTRL, 0xF, 0xF, 0);
  return v + __builtin_bit_cast(float, r);
}
__device__ __forceinline__ float red8(float p) {
  p = dpp_add<0xB1>(p);    // quad_perm(1,0,3,2): xor1
  p = dpp_add<0x4E>(p);    // quad_perm(2,3,0,1): xor2
  p = dpp_add<0x141>(p);   // row_half_mirror: cross-quad within 8
  return p;
}

// ---------------- prep: weight conversions + A*log2e ----------------
__global__ void k_prep(const float* __restrict__ Wxp, const float* __restrict__ Wdt,
                       const float* __restrict__ logA,
                       short* __restrict__ wxp_bf, short* __restrict__ wdt_bf,
                       float* __restrict__ al2) {
  int i = blockIdx.x * 256 + threadIdx.x;
  if (i < 96 * 1024) wxp_bf[i] = f2bf_rne(Wxp[i]);
  if (i < 1024 * 64) wdt_bf[i] = f2bf_rne(Wdt[i]);
  if (i < 1024 * 16) al2[i] = -__expf(logA[i]) * 1.44269504f;
}

// ---------------- proj: xp = x @ Wxp^T  (MFMA bf16, split-K x2) ----------------
// 512 thr = 8 waves. wave w: rows 16*(w&3), K-half w>>2. LDS combine, kh==0 stores.
__global__ __launch_bounds__(512) void k_proj(
    const float* __restrict__ x, const short* __restrict__ wxp_bf,
    short* __restrict__ xp_dt, float* __restrict__ BC) {
  __shared__ f32x4 accsh[4 * 6 * 64];  // 24 KB
  const int w = threadIdx.x >> 6;
  const int l = threadIdx.x & 63;
  const int rg = w & 3;
  const int kh = w >> 2;
  const int cl = l & 15;
  const int q = l >> 4;
  const int kb = q * 8;
  const int row = blockIdx.x * 64 + rg * 16 + cl;

  f32x4 acc[6];
#pragma unroll
  for (int t = 0; t < 6; ++t) acc[t] = (f32x4){0.f, 0.f, 0.f, 0.f};

  const float* xr = x + (size_t)row * DIN + kh * 512 + kb;
  const short* wb = wxp_bf + kh * 512 + kb;
#pragma unroll 2
  for (int k0 = 0; k0 < 512; k0 += 32) {
    float4 p0 = *(const float4*)(xr + k0);
    float4 p1 = *(const float4*)(xr + k0 + 4);
    bf16x8 a;
    a[0] = f2bf_trunc(p0.x); a[1] = f2bf_trunc(p0.y);
    a[2] = f2bf_trunc(p0.z); a[3] = f2bf_trunc(p0.w);
    a[4] = f2bf_trunc(p1.x); a[5] = f2bf_trunc(p1.y);
    a[6] = f2bf_trunc(p1.z); a[7] = f2bf_trunc(p1.w);
#pragma unroll
    for (int t = 0; t < 6; ++t) {
      bf16x8 bb = *(const bf16x8*)(wb + (size_t)(t * 16 + cl) * DIN + k0);
      acc[t] = mfma16(a, bb, acc[t]);
    }
  }
  if (kh == 1) {
#pragma unroll
    for (int t = 0; t < 6; ++t) accsh[(rg * 6 + t) * 64 + l] = acc[t];
  }
  __syncthreads();
  if (kh == 0) {
#pragma unroll
    for (int t = 0; t < 6; ++t) acc[t] += accsh[(rg * 6 + t) * 64 + l];
    const int rbase = blockIdx.x * 64 + rg * 16 + q * 4;
#pragma unroll
    for (int t = 0; t < 4; ++t)
#pragma unroll
      for (int i = 0; i < 4; ++i)
        xp_dt[(size_t)(rbase + i) * 64 + t * 16 + cl] = f2bf_trunc(acc[t][i]);
#pragma unroll
    for (int t = 4; t < 6; ++t)
#pragma unroll
      for (int i = 0; i < 4; ++i)
        BC[(size_t)(rbase + i) * 32 + (t - 4) * 16 + cl] = acc[t][i];
  }
}

// ---------------- phase 1: chunked scan (8 chunks of 256 steps) ----------------
// grid 2048: b=blk>>8, chunk=(blk>>5)&7, dg=blk&31. 256 thr: 32 ch x 8 lanes (2 states).
__global__ __launch_bounds__(256) void k_scan1(
    const float* __restrict__ x, const float* __restrict__ BC,
    const short* __restrict__ xp_dt, const short* __restrict__ wdt_bf,
    const float* __restrict__ bdt, const float* __restrict__ al2,
    const float* __restrict__ Dparam, const unsigned char* __restrict__ pad,
    float* __restrict__ Y, float* __restrict__ Ssum, short* __restrict__ Hfin) {
  __shared__ float x_w[2][65 * 32];
  __shared__ float bc_w[2][65 * 32];
  __shared__ float dt_w[2][65 * 33];
  __shared__ float mk_w[2][72];

  const int tid = threadIdx.x;
  const int w = tid >> 6;
  const int l = tid & 63;
  const int b = blockIdx.x >> 8;
  const int chunk = (blockIdx.x >> 5) & 7;
  const int d0 = (blockIdx.x & 31) * 32;
  const int grp = tid >> 3;
  const int l3 = tid & 7;
  const int n0 = l3 * 2;
  const int d = d0 + grp;
  const int cbase = chunk * 256;

  const float cA0 = al2[d * 16 + n0];
  const float cA1 = al2[d * 16 + n0 + 1];
  const float Dp = Dparam[d];

  const int cl = l & 15;
  const int q = l >> 4;
  const int kb = q * 8;

  bf16x8 bw00 = *(const bf16x8*)(wdt_bf + (size_t)(d0 + cl) * 64 + kb);
  bf16x8 bw01 = *(const bf16x8*)(wdt_bf + (size_t)(d0 + cl) * 64 + 32 + kb);
  bf16x8 bw10 = *(const bf16x8*)(wdt_bf + (size_t)(d0 + 16 + cl) * 64 + kb);
  bf16x8 bw11 = *(const bf16x8*)(wdt_bf + (size_t)(d0 + 16 + cl) * 64 + 32 + kb);
  const float bias0 = bdt[d0 + cl];
  const float bias1 = bdt[d0 + 16 + cl];

  float h0 = 0.f, h1 = 0.f, S = 0.f;

  auto stage = [&](int t0, int buf) {
    const float* xg = x + ((size_t)(b * TLEN + t0)) * DIN + d0;
#pragma unroll
    for (int r = 0; r < 2; ++r) {
      int flat = r * 1024 + w * 256 + l * 4;
      int tt = flat >> 5, cc = flat & 31;
      gl_lds16(xg + (size_t)tt * DIN + cc, &x_w[buf][r * 1024 + w * 256]);
    }
    const float* bg = BC + ((size_t)(b * TLEN + t0)) * 32;
#pragma unroll
    for (int r = 0; r < 2; ++r) {
      int flat = r * 1024 + w * 256 + l * 4;
      gl_lds16(bg + flat, &bc_w[buf][r * 1024 + w * 256]);
    }
    if (tid < 64) mk_w[buf][tid] = pad[b * TLEN + t0 + tid] ? 0.f : 1.f;
  };

  auto dtc = [&](int t0, int buf) {
    const short* ag = xp_dt + ((size_t)(b * TLEN + t0 + w * 16 + cl)) * 64 + kb;
    bf16x8 a0 = *(const bf16x8*)(ag);
    bf16x8 a1 = *(const bf16x8*)(ag + 32);
    f32x4 ac0 = {0.f, 0.f, 0.f, 0.f};
    f32x4 ac1 = {0.f, 0.f, 0.f, 0.f};
    ac0 = mfma16(a0, bw00, ac0);
    ac0 = mfma16(a1, bw01, ac0);
    ac1 = mfma16(a0, bw10, ac1);
    ac1 = mfma16(a1, bw11, ac1);
#pragma unroll
    for (int i = 0; i < 4; ++i) {
      int rowo = (w * 16 + q * 4 + i) * 33;
      dt_w[buf][rowo + cl] = softplus_f(ac0[i] + bias0);
      dt_w[buf][rowo + 16 + cl] = softplus_f(ac1[i] + bias1);
    }
  };

  stage(cbase, 0);
  dtc(cbase, 0);
  __syncthreads();

  for (int win = 0; win < 4; ++win) {
    const int cur = win & 1;
    const int t0 = cbase + win * 64;
    if (win < 3) { stage(t0 + 64, cur ^ 1); dtc(t0 + 64, cur ^ 1); }

    float* yrow = Y + ((size_t)(b * TLEN + t0)) * DIN + d;
    // software-pipelined operand reads (padded +1 row; garbage prefetch at tt=63 unused)
    float dtv = dt_w[cur][grp];
    float xv = x_w[cur][grp];
    f32x2 Bv = *(const f32x2*)&bc_w[cur][n0];
    f32x2 Cv = *(const f32x2*)&bc_w[cur][16 + n0];
    float m = mk_w[cur][0];
#pragma unroll 8
    for (int tt = 0; tt < 64; ++tt) {
      float dtv_n = dt_w[cur][(tt + 1) * 33 + grp];
      float xv_n = x_w[cur][(tt + 1) * 32 + grp];
      f32x2 Bv_n = *(const f32x2*)&bc_w[cur][(tt + 1) * 32 + n0];
      f32x2 Cv_n = *(const f32x2*)&bc_w[cur][(tt + 1) * 32 + 16 + n0];
      float m_n = mk_w[cur][tt + 1];

      float e0 = __builtin_amdgcn_exp2f(cA0 * dtv) * m;
      float e1 = __builtin_amdgcn_exp2f(cA1 * dtv) * m;
      float dtxm = dtv * xv * m;
      h0 = fmaf(e0, h0, dtxm * Bv[0]);
      h1 = fmaf(e1, h1, dtxm * Bv[1]);
      float p = fmaf(h1, Cv[1], h0 * Cv[0]);
      p = red8(p);
      S += (m == 0.f) ? 1e9f : dtv;
      float yv = fmaf(Dp, xv * m, p);
      if (l3 == 0) yrow[(size_t)tt * DIN] = yv;

      dtv = dtv_n; xv = xv_n; Bv = Bv_n; Cv = Cv_n; m = m_n;
    }
    __syncthreads();
  }

  if (l3 == 0) Ssum[(size_t)(b * 8 + chunk) * 1024 + d] = S;
  size_t hoff = ((size_t)(b * 8 + chunk) * 1024 + d) * 16;
  Hfin[hoff + n0] = f2bf_rne(h0);
  Hfin[hoff + n0 + 1] = f2bf_rne(h1);
}

// ---------------- phase 2: cross-chunk fixup  Y += C·(cumA ⊙ h_in) ----------------
// grid 1792 (chunks 1..7). 256 thr: 32 ch x 8 lanes; lane owns 8 contiguous t per window.
__global__ __launch_bounds__(256) void k_fix(
    const float* __restrict__ BC, const short* __restrict__ xp_dt,
    const short* __restrict__ wdt_bf, const float* __restrict__ bdt,
    const float* __restrict__ al2, const unsigned char* __restrict__ pad,
    const float* __restrict__ Ssum, const short* __restrict__ Hfin,
    float* __restrict__ Y) {
  __shared__ float dt_w[2][65 * 33];
  __shared__ float part[2][256];

  const int tid = threadIdx.x;
  const int w = tid >> 6;
  const int l = tid & 63;
  const int dg = blockIdx.x & 31;
  const int qq = blockIdx.x >> 5;
  const int chunk = (qq % 7) + 1;
  const int b = qq / 7;
  const int d0 = dg * 32;
  const int grp = tid >> 3;
  const int l3 = tid & 7;
  const int d = d0 + grp;
  const int cb = chunk * 256;

  const int cl = l & 15;
  const int q = l >> 4;
  const int kb = q * 8;

  bf16x8 bw00 = *(const bf16x8*)(wdt_bf + (size_t)(d0 + cl) * 64 + kb);
  bf16x8 bw01 = *(const bf16x8*)(wdt_bf + (size_t)(d0 + cl) * 64 + 32 + kb);
  bf16x8 bw10 = *(const bf16x8*)(wdt_bf + (size_t)(d0 + 16 + cl) * 64 + kb);
  bf16x8 bw11 = *(const bf16x8*)(wdt_bf + (size_t)(d0 + 16 + cl) * 64 + 32 + kb);
  const float bias0 = bdt[d0 + cl];
  const float bias1 = bdt[d0 + 16 + cl];

  auto dtc = [&](int t0, int buf) {
    const short* ag = xp_dt + ((size_t)(b * TLEN + t0 + w * 16 + cl)) * 64 + kb;
    bf16x8 a0 = *(const bf16x8*)(ag);
    bf16x8 a1 = *(const bf16x8*)(ag + 32);
    f32x4 ac0 = {0.f, 0.f, 0.f, 0.f};
    f32x4 ac1 = {0.f, 0.f, 0.f, 0.f};
    ac0 = mfma16(a0, bw00, ac0);
    ac0 = mfma16(a1, bw01, ac0);
    ac1 = mfma16(a0, bw10, ac1);
    ac1 = mfma16(a1, bw11, ac1);
#pragma unroll
    for (int i = 0; i < 4; ++i) {
      int rowo = (w * 16 + q * 4 + i) * 33;
      dt_w[buf][rowo + cl] = softplus_f(ac0[i] + bias0);
      dt_w[buf][rowo + 16 + cl] = softplus_f(ac1[i] + bias1);
    }
  };

  // h_in[16] = fold of chunk summaries 0..chunk-1 ; cA[16]
  float cA[16], hin[16];
#pragma unroll
  for (int n = 0; n < 16; ++n) { cA[n] = al2[d * 16 + n]; hin[n] = 0.f; }
  for (int c = 0; c < chunk; ++c) {
    float s = Ssum[(size_t)(b * 8 + c) * 1024 + d];
    const short* hf = Hfin + ((size_t)(b * 8 + c) * 1024 + d) * 16;
#pragma unroll
    for (int n = 0; n < 16; ++n)
      hin[n] = fmaf(__builtin_amdgcn_exp2f(cA[n] * s), hin[n], bf2f(hf[n]));
  }

  dtc(cb, 0);
  __syncthreads();

  float carry = 0.f;
  for (int win = 0; win < 4; ++win) {
    const int buf = win & 1;
    const int t0 = cb + win * 64;
    if (win < 3) dtc(t0 + 64, buf ^ 1);

    // own 8 effective dt (masked -> 1e9), partial sum
    uint64_t pv = *(const uint64_t*)(pad + (size_t)b * TLEN + t0 + l3 * 8);
    float deff[8];
    float P = 0.f;
#pragma unroll
    for (int i = 0; i < 8; ++i) {
      float dtv = dt_w[buf][(l3 * 8 + i) * 33 + grp];
      deff[i] = ((pv >> (8 * i)) & 0xFFull) ? 1e9f : dtv;
      P += deff[i];
    }
    part[buf][tid] = P;
    __syncthreads();

    float base = carry, tot = 0.f;
#pragma unroll
    for (int j = 0; j < 8; ++j) {
      float pj = part[buf][grp * 8 + j];
      tot += pj;
      base += (j < l3) ? pj : 0.f;
    }

    float S = base;
#pragma unroll 2
    for (int i = 0; i < 8; ++i) {
      S += deff[i];
      int tg = t0 + l3 * 8 + i;
      const float4* Crow = (const float4*)(BC + ((size_t)(b * TLEN + tg)) * 32 + 16);
      float cv[16];
      *(float4*)&cv[0] = Crow[0];
      *(float4*)&cv[4] = Crow[1];
      *(float4*)&cv[8] = Crow[2];
      *(float4*)&cv[12] = Crow[3];
      float fix = 0.f;
#pragma unroll
      for (int n = 0; n < 16; ++n)
        fix = fmaf(cv[n] * __builtin_amdgcn_exp2f(cA[n] * S), hin[n], fix);
      float* yp = Y + ((size_t)(b * TLEN + tg)) * DIN + d;
      *yp += fix;
    }
    carry += tot;
  }
}

extern "C" void kernel_launch(void* const* d_in, const int* in_sizes, int n_in,
                              void* d_out, int out_size, void* d_ws, size_t ws_size,
                              hipStream_t stream) {
  const float* x = (const float*)d_in[0];
  const unsigned char* pad = (const unsigned char*)d_in[1];
  const float* Wxp = (const float*)d_in[2];
  const float* Wdt = (const float*)d_in[3];
  const float* bdt = (const float*)d_in[4];
  const float* logA = (const float*)d_in[5];
  const float* Dpar = (const float*)d_in[6];
  float* Y = (float*)d_out;

  char* ws = (char*)d_ws;
  short* wxp_bf = (short*)(ws);                 // 196608
  short* wdt_bf = (short*)(ws + 196608);        // 131072
  float* al2    = (float*)(ws + 327680);        // 65536
  short* xp_dt  = (short*)(ws + 393216);        // 2097152
  float* BC     = (float*)(ws + 2490368);       // 2097152
  float* Ssum   = (float*)(ws + 4587520);       // 262144
  short* Hfin   = (short*)(ws + 4849664);       // 2097152  (total ~6.9 MB)

  hipLaunchKernelGGL(k_prep, dim3(384), dim3(256), 0, stream,
                     Wxp, Wdt, logA, wxp_bf, wdt_bf, al2);
  hipLaunchKernelGGL(k_proj, dim3(256), dim3(512), 0, stream,
                     x, wxp_bf, xp_dt, BC);
  hipLaunchKernelGGL(k_scan1, dim3(2048), dim3(256), 0, stream,
                     x, BC, xp_dt, wdt_bf, bdt, al2, Dpar, pad, Y, Ssum, Hfin);
  hipLaunchKernelGGL(k_fix, dim3(1792), dim3(256), 0, stream,
                     BC, xp_dt, wdt_bf, bdt, al2, pad, Ssum, Hfin, Y);
}

// Round 3
// 274.227 us; speedup vs baseline: 1.9949x; 1.4543x over previous
//
#include <hip/hip_runtime.h>
#include <stdint.h>

#define DIN 1024
#define TLEN 2048
#define NCH 16     // chunks
#define CHT 128    // steps per chunk
#define WIN 32     // window (t per LDS tile)

typedef __attribute__((ext_vector_type(8))) short bf16x8;
typedef __attribute__((ext_vector_type(4))) float f32x4;

__device__ __forceinline__ short f2bf_trunc(float f) {
  union { float f; uint32_t u; } v; v.f = f;
  return (short)(v.u >> 16);
}
__device__ __forceinline__ short f2bf_rne(float f) {
  union { float f; uint32_t u; } v; v.f = f;
  uint32_t r = v.u + 0x7FFFu + ((v.u >> 16) & 1u);
  return (short)(r >> 16);
}
__device__ __forceinline__ float bf2f(short s) {
  union { uint32_t u; float f; } v; v.u = ((uint32_t)(unsigned short)s) << 16;
  return v.f;
}
__device__ __forceinline__ uint32_t pack_bf2(float a, float b) {
  union { float f; uint32_t u; } va, vb; va.f = a; vb.f = b;
  return (va.u >> 16) | (vb.u & 0xFFFF0000u);
}
__device__ __forceinline__ float softplus_f(float v) {
  float e = __builtin_amdgcn_exp2f(v * 1.44269504f);
  float sp = __builtin_amdgcn_logf(1.0f + e) * 0.6931471806f;
  return v > 15.0f ? v : sp;
}
__device__ __forceinline__ void gl_lds16(const void* g, void* l) {
  __builtin_amdgcn_global_load_lds(
      (const __attribute__((address_space(1))) uint32_t*)g,
      (__attribute__((address_space(3))) uint32_t*)l, 16, 0, 0);
}
__device__ __forceinline__ f32x4 mfma16(bf16x8 a, bf16x8 b, f32x4 c) {
  return __builtin_amdgcn_mfma_f32_16x16x32_bf16(a, b, c, 0, 0, 0);
}
template <int CTRL>
__device__ __forceinline__ float dpp_add(float v) {
  int r = __builtin_amdgcn_update_dpp(0, __builtin_bit_cast(int, v), CTRL, 0xF, 0xF, 0);
  return v + __builtin_bit_cast(float, r);
}

// ---------------- prep: weight conversions + A*log2e + pad bitmask ----------------
__global__ void k_prep(const float* __restrict__ Wxp, const float* __restrict__ Wdt,
                       const float* __restrict__ logA, const unsigned char* __restrict__ pad,
                       short* __restrict__ wxp_bf, short* __restrict__ wdt_bf,
                       float* __restrict__ al2, uint32_t* __restrict__ padbits) {
  int i = blockIdx.x * 256 + threadIdx.x;
  if (i < 96 * 1024) wxp_bf[i] = f2bf_rne(Wxp[i]);
  if (i < 1024 * 64) wdt_bf[i] = f2bf_rne(Wdt[i]);
  if (i < 1024 * 16) al2[i] = -__expf(logA[i]) * 1.44269504f;
  if (i < 512) {
    uint32_t m = 0;
    const unsigned char* p = pad + (size_t)i * 32;
    for (int j = 0; j < 32; ++j) m |= (p[j] ? 1u : 0u) << j;
    padbits[i] = m;
  }
}

// ---------------- proj: xp = x @ Wxp^T (operand-swapped MFMA) ----------------
// grid 512, 256 thr = 4 waves: wave = (rh = w&1: 16 t-rows, ch = w>>1: 3 col-tiles)
__global__ __launch_bounds__(256) void k_proj(
    const float* __restrict__ x, const short* __restrict__ wxp_bf,
    short* __restrict__ xp_dt, float* __restrict__ BC) {
  const int w = threadIdx.x >> 6, l = threadIdx.x & 63;
  const int cl = l & 15, q = l >> 4, kb = q * 8;
  const int rh = w & 1, ch = w >> 1;
  const int xrow = blockIdx.x * 32 + rh * 16 + cl;

  f32x4 acc[3];
#pragma unroll
  for (int t = 0; t < 3; ++t) acc[t] = (f32x4){0.f, 0.f, 0.f, 0.f};

  const float* xr = x + (size_t)xrow * DIN + kb;
  const short* wb = wxp_bf + (size_t)(ch * 48 + cl) * DIN + kb;
#pragma unroll 2
  for (int k0 = 0; k0 < DIN; k0 += 32) {
    float4 p0 = *(const float4*)(xr + k0);
    float4 p1 = *(const float4*)(xr + k0 + 4);
    bf16x8 xb;
    xb[0] = f2bf_trunc(p0.x); xb[1] = f2bf_trunc(p0.y);
    xb[2] = f2bf_trunc(p0.z); xb[3] = f2bf_trunc(p0.w);
    xb[4] = f2bf_trunc(p1.x); xb[5] = f2bf_trunc(p1.y);
    xb[6] = f2bf_trunc(p1.z); xb[7] = f2bf_trunc(p1.w);
#pragma unroll
    for (int t = 0; t < 3; ++t) {
      bf16x8 wf = *(const bf16x8*)(wb + (size_t)t * 16 * DIN + k0);
      acc[t] = mfma16(wf, xb, acc[t]);  // D[outcol(q*4+i)][xrow(cl)]
    }
  }
#pragma unroll
  for (int t = 0; t < 3; ++t) {
    int oc = ch * 48 + t * 16 + q * 4;
    if (oc < 64) {
      uint2 uu;
      uu.x = pack_bf2(acc[t][0], acc[t][1]);
      uu.y = pack_bf2(acc[t][2], acc[t][3]);
      *(uint2*)(xp_dt + (size_t)xrow * 64 + oc) = uu;
    } else {
      *(f32x4*)(BC + (size_t)xrow * 32 + (oc - 64)) = acc[t];
    }
  }
}

// ---------------- phase 1: chunked scan. 64 d x 4 lanes (4 states each) ----------------
// grid 2048: b=blk>>8, chunk=(blk>>4)&15, dg=blk&15.
__global__ __launch_bounds__(256) void k_scan1(
    const float* __restrict__ x, const float* __restrict__ BC,
    const short* __restrict__ xp_dt, const short* __restrict__ wdt_bf,
    const float* __restrict__ bdt, const float* __restrict__ al2,
    const float* __restrict__ Dparam, const uint32_t* __restrict__ padbits,
    float* __restrict__ Y, float* __restrict__ Ssum, short* __restrict__ Hfin) {
  __shared__ float x_w[2][33 * 64];
  __shared__ float bc_w[2][33 * 32];
  __shared__ float dt_w[2][33 * 68];

  const int tid = threadIdx.x;
  const int w = tid >> 6, l = tid & 63;
  const int cl = l & 15, q = l >> 4, kb = q * 8;
  const int dg = blockIdx.x & 15;
  const int chunk = (blockIdx.x >> 4) & 15;
  const int b = blockIdx.x >> 8;
  const int d0 = dg * 64;
  const int cb = chunk * CHT;
  const int grp = tid >> 2, l2 = tid & 3, n0 = l2 * 4;
  const int d = d0 + grp;

  const f32x4 cA = *(const f32x4*)(al2 + (size_t)d * 16 + n0);
  const float Dp = Dparam[d];

  const int th = w & 1, dh = w >> 1;
  // A-frags: Wdt rows (d) for this wave's 2 d-tiles
  const short* wr0 = wdt_bf + (size_t)(d0 + dh * 32 + cl) * 64 + kb;
  const short* wr1 = wdt_bf + (size_t)(d0 + dh * 32 + 16 + cl) * 64 + kb;
  bf16x8 aw00 = *(const bf16x8*)(wr0);
  bf16x8 aw01 = *(const bf16x8*)(wr0 + 32);
  bf16x8 aw10 = *(const bf16x8*)(wr1);
  bf16x8 aw11 = *(const bf16x8*)(wr1 + 32);
  f32x4 bias0 = *(const f32x4*)(bdt + d0 + dh * 32 + q * 4);
  f32x4 bias1 = *(const f32x4*)(bdt + d0 + dh * 32 + 16 + q * 4);

  float h[4] = {0.f, 0.f, 0.f, 0.f};
  float S = 0.f;

  auto stage = [&](int t0, int buf) {
    const float* xg = x + ((size_t)(b * TLEN + t0)) * DIN + d0;
#pragma unroll
    for (int r = 0; r < 2; ++r) {
      int flat = r * 1024 + w * 256 + l * 4;
      int tt = flat >> 6, cc = flat & 63;
      gl_lds16(xg + (size_t)tt * DIN + cc, &x_w[buf][r * 1024 + w * 256]);
    }
    const float* bg = BC + ((size_t)(b * TLEN + t0)) * 32;
    gl_lds16(bg + w * 256 + l * 4, &bc_w[buf][w * 256]);
  };

  auto dtc = [&](int t0, int buf) {
    uint32_t mw = padbits[b * 64 + (t0 >> 5)];
    int tloc = th * 16 + cl;
    bool masked = (mw >> tloc) & 1;
    const short* ag = xp_dt + (size_t)(b * TLEN + t0 + tloc) * 64 + kb;
    bf16x8 b0 = *(const bf16x8*)(ag);
    bf16x8 b1 = *(const bf16x8*)(ag + 32);
    f32x4 ac = mfma16(aw00, b0, (f32x4){0.f, 0.f, 0.f, 0.f});
    ac = mfma16(aw01, b1, ac);
    f32x4 dv;
#pragma unroll
    for (int i = 0; i < 4; ++i) {
      float sp = softplus_f(ac[i] + bias0[i]);
      dv[i] = masked ? 1e9f : sp;
    }
    *(f32x4*)&dt_w[buf][tloc * 68 + dh * 32 + q * 4] = dv;
    ac = mfma16(aw10, b0, (f32x4){0.f, 0.f, 0.f, 0.f});
    ac = mfma16(aw11, b1, ac);
#pragma unroll
    for (int i = 0; i < 4; ++i) {
      float sp = softplus_f(ac[i] + bias1[i]);
      dv[i] = masked ? 1e9f : sp;
    }
    *(f32x4*)&dt_w[buf][tloc * 68 + dh * 32 + 16 + q * 4] = dv;
  };

  stage(cb, 0);
  dtc(cb, 0);
  __syncthreads();

  for (int win = 0; win < CHT / WIN; ++win) {
    const int curb = win & 1;
    const int t0 = cb + win * WIN;
    if (win < CHT / WIN - 1) { stage(t0 + WIN, curb ^ 1); dtc(t0 + WIN, curb ^ 1); }

    float* ybase = Y + ((size_t)(b * TLEN + t0)) * DIN + d;
    float dtv = dt_w[curb][grp];
    float xv = x_w[curb][grp];
    f32x4 Bv = *(const f32x4*)&bc_w[curb][n0];
    f32x4 Cv = *(const f32x4*)&bc_w[curb][16 + n0];
#pragma unroll 8
    for (int tt = 0; tt < WIN; ++tt) {
      float dtv_n = dt_w[curb][(tt + 1) * 68 + grp];
      float xv_n = x_w[curb][(tt + 1) * 64 + grp];
      f32x4 Bv_n = *(const f32x4*)&bc_w[curb][(tt + 1) * 32 + n0];
      f32x4 Cv_n = *(const f32x4*)&bc_w[curb][(tt + 1) * 32 + 16 + n0];

      bool live = dtv < 1e8f;
      float dtx = live ? dtv * xv : 0.f;
#pragma unroll
      for (int n = 0; n < 4; ++n) {
        float e = __builtin_amdgcn_exp2f(cA[n] * dtv);
        h[n] = fmaf(e, h[n], dtx * Bv[n]);
      }
      float p = h[0] * Cv[0];
      p = fmaf(h[1], Cv[1], p);
      p = fmaf(h[2], Cv[2], p);
      p = fmaf(h[3], Cv[3], p);
      p = dpp_add<0xB1>(p);  // quad xor1
      p = dpp_add<0x4E>(p);  // quad xor2
      S += dtv;
      float yv = live ? fmaf(Dp, xv, p) : 0.f;
      if (l2 == 0) ybase[(size_t)tt * DIN] = yv;

      dtv = dtv_n; xv = xv_n; Bv = Bv_n; Cv = Cv_n;
    }
    __syncthreads();
  }

  if (l2 == 0) Ssum[(size_t)(b * NCH + chunk) * 1024 + d] = S;
  short4 hs;
  hs.x = f2bf_rne(h[0]); hs.y = f2bf_rne(h[1]);
  hs.z = f2bf_rne(h[2]); hs.w = f2bf_rne(h[3]);
  *(short4*)(Hfin + ((size_t)(b * NCH + chunk) * 1024 + d) * 16 + n0) = hs;
}

// ---------------- phase 2: coalesced fixup. thread owns one d, t-serial ----------------
// grid 480 = 8 b x 15 chunks x 4 dblk(256 d)
__global__ __launch_bounds__(256) void k_fix(
    const float* __restrict__ BC, const short* __restrict__ xp_dt,
    const short* __restrict__ wdt_bf, const float* __restrict__ bdt,
    const float* __restrict__ al2, const uint32_t* __restrict__ padbits,
    const float* __restrict__ Ssum, const short* __restrict__ Hfin,
    float* __restrict__ Y) {
  __shared__ float dtw[32 * 260];
  __shared__ float c_w[32 * 16];

  const int tid = threadIdx.x;
  const int w = tid >> 6, l = tid & 63;
  const int cl = l & 15, q = l >> 4, kb = q * 8;
  const int b = blockIdx.x / 60;
  const int rem = blockIdx.x % 60;
  const int chunk = (rem >> 2) + 1;
  const int dblk = rem & 3;
  const int d = dblk * 256 + tid;
  const int th = w & 1, dh = w >> 1;

  float cA[16], hin[16];
#pragma unroll
  for (int g = 0; g < 4; ++g)
    *(f32x4*)&cA[g * 4] = *(const f32x4*)(al2 + (size_t)d * 16 + g * 4);
#pragma unroll
  for (int n = 0; n < 16; ++n) hin[n] = 0.f;

  for (int c = 0; c < chunk; ++c) {
    float s = Ssum[(size_t)(b * NCH + c) * 1024 + d];
    const short4* hp = (const short4*)(Hfin + ((size_t)(b * NCH + c) * 1024 + d) * 16);
#pragma unroll
    for (int g = 0; g < 4; ++g) {
      short4 hv = hp[g];
      hin[g * 4 + 0] = fmaf(__builtin_amdgcn_exp2f(cA[g * 4 + 0] * s), hin[g * 4 + 0], bf2f(hv.x));
      hin[g * 4 + 1] = fmaf(__builtin_amdgcn_exp2f(cA[g * 4 + 1] * s), hin[g * 4 + 1], bf2f(hv.y));
      hin[g * 4 + 2] = fmaf(__builtin_amdgcn_exp2f(cA[g * 4 + 2] * s), hin[g * 4 + 2], bf2f(hv.z));
      hin[g * 4 + 3] = fmaf(__builtin_amdgcn_exp2f(cA[g * 4 + 3] * s), hin[g * 4 + 3], bf2f(hv.w));
    }
  }

  float S = 0.f;
  for (int win = 0; win < CHT / WIN; ++win) {
    const int t0 = chunk * CHT + win * WIN;
    __syncthreads();  // safe to overwrite dtw/c_w
    if (w == 0) {
      gl_lds16(BC + ((size_t)(b * TLEN + t0 + (l >> 2))) * 32 + 16 + (l & 3) * 4, &c_w[0]);
      gl_lds16(BC + ((size_t)(b * TLEN + t0 + 16 + (l >> 2))) * 32 + 16 + (l & 3) * 4, &c_w[256]);
    }
    uint32_t mw = padbits[b * 64 + (t0 >> 5)];
    const int tloc = th * 16 + cl;
    const bool masked = (mw >> tloc) & 1;
    const short* ag = xp_dt + (size_t)(b * TLEN + t0 + tloc) * 64 + kb;
    bf16x8 xb0 = *(const bf16x8*)(ag);
    bf16x8 xb1 = *(const bf16x8*)(ag + 32);
#pragma unroll
    for (int dti = 0; dti < 8; ++dti) {
      int dd = dh * 128 + dti * 16;
      const short* wr = wdt_bf + (size_t)(dblk * 256 + dd + cl) * 64 + kb;
      bf16x8 a0 = *(const bf16x8*)(wr);
      bf16x8 a1 = *(const bf16x8*)(wr + 32);
      f32x4 ac = mfma16(a0, xb0, (f32x4){0.f, 0.f, 0.f, 0.f});
      ac = mfma16(a1, xb1, ac);
      f32x4 bv = *(const f32x4*)(bdt + dblk * 256 + dd + q * 4);
      f32x4 dv;
#pragma unroll
      for (int i = 0; i < 4; ++i) {
        float sp = softplus_f(ac[i] + bv[i]);
        dv[i] = masked ? 1e9f : sp;
      }
      *(f32x4*)&dtw[tloc * 260 + dd + q * 4] = dv;
    }
    __syncthreads();

    float* yb = Y + ((size_t)(b * TLEN + t0)) * DIN + d;
#pragma unroll
    for (int g = 0; g < 4; ++g) {
      float yv[8], de[8];
#pragma unroll
      for (int i = 0; i < 8; ++i) yv[i] = yb[(size_t)(g * 8 + i) * DIN];
#pragma unroll
      for (int i = 0; i < 8; ++i) de[i] = dtw[(g * 8 + i) * 260 + tid];
#pragma unroll
      for (int i = 0; i < 8; ++i) {
        S += de[i];
        float fix = 0.f;
        const f32x4* Ct = (const f32x4*)&c_w[(g * 8 + i) * 16];
#pragma unroll
        for (int n4 = 0; n4 < 4; ++n4) {
          f32x4 cv = Ct[n4];
#pragma unroll
          for (int j = 0; j < 4; ++j) {
            float e = __builtin_amdgcn_exp2f(cA[n4 * 4 + j] * S);
            fix = fmaf(e * cv[j], hin[n4 * 4 + j], fix);
          }
        }
        yv[i] += fix;
      }
#pragma unroll
      for (int i = 0; i < 8; ++i) yb[(size_t)(g * 8 + i) * DIN] = yv[i];
    }
  }
}

extern "C" void kernel_launch(void* const* d_in, const int* in_sizes, int n_in,
                              void* d_out, int out_size, void* d_ws, size_t ws_size,
                              hipStream_t stream) {
  const float* x = (const float*)d_in[0];
  const unsigned char* pad = (const unsigned char*)d_in[1];
  const float* Wxp = (const float*)d_in[2];
  const float* Wdt = (const float*)d_in[3];
  const float* bdt = (const float*)d_in[4];
  const float* logA = (const float*)d_in[5];
  const float* Dpar = (const float*)d_in[6];
  float* Y = (float*)d_out;

  char* ws = (char*)d_ws;
  short* wxp_bf    = (short*)(ws);                 // 196608
  short* wdt_bf    = (short*)(ws + 196608);        // 131072
  float* al2       = (float*)(ws + 327680);        // 65536
  short* xp_dt     = (short*)(ws + 393216);        // 2097152
  float* BC        = (float*)(ws + 2490368);       // 2097152
  float* Ssum      = (float*)(ws + 4587520);       // 524288
  short* Hfin      = (short*)(ws + 5111808);       // 4194304
  uint32_t* padbits= (uint32_t*)(ws + 9306112);    // 2048  (total ~9.31 MB)

  hipLaunchKernelGGL(k_prep, dim3(384), dim3(256), 0, stream,
                     Wxp, Wdt, logA, pad, wxp_bf, wdt_bf, al2, padbits);
  hipLaunchKernelGGL(k_proj, dim3(512), dim3(256), 0, stream,
                     x, wxp_bf, xp_dt, BC);
  hipLaunchKernelGGL(k_scan1, dim3(2048), dim3(256), 0, stream,
                     x, BC, xp_dt, wdt_bf, bdt, al2, Dpar, padbits, Y, Ssum, Hfin);
  hipLaunchKernelGGL(k_fix, dim3(480), dim3(256), 0, stream,
                     BC, xp_dt, wdt_bf, bdt, al2, padbits, Ssum, Hfin, Y);
}

// Round 4
// 259.996 us; speedup vs baseline: 2.1041x; 1.0547x over previous
//
#include <hip/hip_runtime.h>
#include <stdint.h>

#define DIN 1024
#define TLEN 2048
#define NCH 16     // chunks
#define CHT 128    // steps per chunk
#define WIN 32     // window (t per LDS tile)

typedef __attribute__((ext_vector_type(8))) short bf16x8;
typedef __attribute__((ext_vector_type(4))) float f32x4;

__device__ __forceinline__ short f2bf_trunc(float f) {
  union { float f; uint32_t u; } v; v.f = f;
  return (short)(v.u >> 16);
}
__device__ __forceinline__ short f2bf_rne(float f) {
  union { float f; uint32_t u; } v; v.f = f;
  uint32_t r = v.u + 0x7FFFu + ((v.u >> 16) & 1u);
  return (short)(r >> 16);
}
__device__ __forceinline__ float bf2f(short s) {
  union { uint32_t u; float f; } v; v.u = ((uint32_t)(unsigned short)s) << 16;
  return v.f;
}
__device__ __forceinline__ uint32_t pack_bf2_rne(float a, float b) {
  return (uint32_t)(uint16_t)f2bf_rne(a) | ((uint32_t)(uint16_t)f2bf_rne(b) << 16);
}
__device__ __forceinline__ float softplus_f(float v) {
  float e = __builtin_amdgcn_exp2f(v * 1.44269504f);
  float sp = __builtin_amdgcn_logf(1.0f + e) * 0.6931471806f;
  return v > 15.0f ? v : sp;
}
__device__ __forceinline__ void gl_lds16(const void* g, void* l) {
  __builtin_amdgcn_global_load_lds(
      (const __attribute__((address_space(1))) uint32_t*)g,
      (__attribute__((address_space(3))) uint32_t*)l, 16, 0, 0);
}
__device__ __forceinline__ f32x4 mfma16(bf16x8 a, bf16x8 b, f32x4 c) {
  return __builtin_amdgcn_mfma_f32_16x16x32_bf16(a, b, c, 0, 0, 0);
}
template <int CTRL>
__device__ __forceinline__ float dpp_add(float v) {
  int r = __builtin_amdgcn_update_dpp(0, __builtin_bit_cast(int, v), CTRL, 0xF, 0xF, 0);
  return v + __builtin_bit_cast(float, r);
}

// ---------------- prep: weight conversions + A*log2e + pad bitmask ----------------
__global__ void k_prep(const float* __restrict__ Wxp, const float* __restrict__ Wdt,
                       const float* __restrict__ logA, const unsigned char* __restrict__ pad,
                       short* __restrict__ wxp_bf, short* __restrict__ wdt_bf,
                       float* __restrict__ al2, uint32_t* __restrict__ padbits) {
  int i = blockIdx.x * 256 + threadIdx.x;
  if (i < 96 * 1024) wxp_bf[i] = f2bf_rne(Wxp[i]);
  if (i < 1024 * 64) wdt_bf[i] = f2bf_rne(Wdt[i]);
  if (i < 1024 * 16) al2[i] = -__expf(logA[i]) * 1.44269504f;
  if (i < 512) {
    uint32_t m = 0;
    const unsigned char* p = pad + (size_t)i * 32;
    for (int j = 0; j < 32; ++j) m |= (p[j] ? 1u : 0u) << j;
    padbits[i] = m;
  }
}

// ---------------- proj: xp = x @ Wxp^T, LDS-staged coalesced x ----------------
// grid 512 (32 t-rows each), 256 thr = 4 waves: rt=w&1 (rowtile), ch3=w>>1 (3 coltiles)
__global__ __launch_bounds__(256) void k_proj(
    const float* __restrict__ x, const short* __restrict__ wxp_bf,
    short* __restrict__ xp_dt, float* __restrict__ BC) {
  __shared__ float xs[2][32 * 64];
  const int tid = threadIdx.x;
  const int w = tid >> 6, l = tid & 63;
  const int cl = l & 15, q = l >> 4, kb = q * 8;
  const int rt = w & 1, ch3 = w >> 1;
  const int row0 = blockIdx.x * 32;

  f32x4 acc[3];
#pragma unroll
  for (int t = 0; t < 3; ++t) acc[t] = (f32x4){0.f, 0.f, 0.f, 0.f};

  auto stage = [&](int k0, int buf) {
#pragma unroll
    for (int r = 0; r < 2; ++r) {
      int flat = r * 1024 + tid * 4;
      int row = flat >> 6, c0 = flat & 63;
      int swc = c0 ^ ((row & 15) << 2);   // inverse-swizzled source, linear LDS dest
      gl_lds16(x + (size_t)(row0 + row) * DIN + k0 + swc,
               &xs[buf][r * 1024 + w * 256]);
    }
  };

  stage(0, 0);
  __syncthreads();
  const int Xr = cl << 2;
  for (int k0 = 0; k0 < DIN; k0 += 64) {
    const int buf = (k0 >> 6) & 1;
    if (k0 < DIN - 64) stage(k0 + 64, buf ^ 1);
#pragma unroll
    for (int kk = 0; kk < 64; kk += 32) {
      const float* xr = &xs[buf][(rt * 16 + cl) * 64];
      float4 fa = *(const float4*)&xr[(kk + kb) ^ Xr];
      float4 fb = *(const float4*)&xr[(kk + kb + 4) ^ Xr];
      bf16x8 xb;
      xb[0] = f2bf_trunc(fa.x); xb[1] = f2bf_trunc(fa.y);
      xb[2] = f2bf_trunc(fa.z); xb[3] = f2bf_trunc(fa.w);
      xb[4] = f2bf_trunc(fb.x); xb[5] = f2bf_trunc(fb.y);
      xb[6] = f2bf_trunc(fb.z); xb[7] = f2bf_trunc(fb.w);
#pragma unroll
      for (int t = 0; t < 3; ++t) {
        bf16x8 wf = *(const bf16x8*)(wxp_bf + (size_t)(ch3 * 48 + t * 16 + cl) * DIN + k0 + kk + kb);
        acc[t] = mfma16(wf, xb, acc[t]);  // D[outcol][xrow]
      }
    }
    __syncthreads();
  }
  const int xrow = row0 + rt * 16 + cl;
#pragma unroll
  for (int t = 0; t < 3; ++t) {
    int oc = ch3 * 48 + t * 16 + q * 4;
    if (oc < 64) {
      uint2 uu;
      uu.x = pack_bf2_rne(acc[t][0], acc[t][1]);
      uu.y = pack_bf2_rne(acc[t][2], acc[t][3]);
      *(uint2*)(xp_dt + (size_t)xrow * 64 + oc) = uu;
    } else {
      *(f32x4*)(BC + (size_t)xrow * 32 + (oc - 64)) = acc[t];
    }
  }
}

// ---------------- pass 1: chunk summaries only (h_fin, S). No y/C/dot ----------------
// grid 2048: b=blk>>8, chunk=(blk>>4)&15, dg=blk&15. 64 d x 4 lanes (4 states each).
__global__ __launch_bounds__(256) void k_sc1(
    const float* __restrict__ x, const float* __restrict__ BC,
    const short* __restrict__ xp_dt, const short* __restrict__ wdt_bf,
    const float* __restrict__ bdt, const float* __restrict__ al2,
    const uint32_t* __restrict__ padbits,
    float* __restrict__ Ssum, short* __restrict__ Hio) {
  __shared__ float x_w[2][33 * 64];
  __shared__ short dt_w[2][33 * 68];
  __shared__ float b_w[2][33 * 16];

  const int tid = threadIdx.x;
  const int w = tid >> 6, l = tid & 63;
  const int cl = l & 15, q = l >> 4, kb = q * 8;
  const int dg = blockIdx.x & 15;
  const int chunk = (blockIdx.x >> 4) & 15;
  const int b = blockIdx.x >> 8;
  const int d0 = dg * 64;
  const int cb = chunk * CHT;
  const int grp = tid >> 2, l2 = tid & 3, n0 = l2 * 4;
  const int d = d0 + grp;
  const int th = w & 1, dh = w >> 1;

  const f32x4 cA = *(const f32x4*)(al2 + (size_t)d * 16 + n0);

  const short* wr0 = wdt_bf + (size_t)(d0 + dh * 32 + cl) * 64 + kb;
  const short* wr1 = wdt_bf + (size_t)(d0 + dh * 32 + 16 + cl) * 64 + kb;
  bf16x8 aw00 = *(const bf16x8*)(wr0);
  bf16x8 aw01 = *(const bf16x8*)(wr0 + 32);
  bf16x8 aw10 = *(const bf16x8*)(wr1);
  bf16x8 aw11 = *(const bf16x8*)(wr1 + 32);
  f32x4 bias0 = *(const f32x4*)(bdt + d0 + dh * 32 + q * 4);
  f32x4 bias1 = *(const f32x4*)(bdt + d0 + dh * 32 + 16 + q * 4);

  float h[4] = {0.f, 0.f, 0.f, 0.f};
  float S = 0.f;

  auto stage = [&](int t0, int buf) {
    const float* xg = x + ((size_t)(b * TLEN + t0)) * DIN + d0;
#pragma unroll
    for (int r = 0; r < 2; ++r) {
      int flat = r * 1024 + w * 256 + l * 4;
      int tt = flat >> 6, cc = flat & 63;
      gl_lds16(xg + (size_t)tt * DIN + cc, &x_w[buf][r * 1024 + w * 256]);
    }
    if (w < 2) {
      int flat = w * 256 + l * 4;
      int tt = flat >> 4, cc = flat & 15;
      gl_lds16(BC + ((size_t)(b * TLEN + t0 + tt)) * 32 + cc, &b_w[buf][w * 256]);
    }
  };

  auto dtc = [&](int t0, int buf) {
    uint32_t mw = padbits[b * 64 + (t0 >> 5)];
    int tloc = th * 16 + cl;
    bool masked = (mw >> tloc) & 1;
    const short* ag = xp_dt + (size_t)(b * TLEN + t0 + tloc) * 64 + kb;
    bf16x8 b0 = *(const bf16x8*)(ag);
    bf16x8 b1 = *(const bf16x8*)(ag + 32);
    f32x4 ac = mfma16(aw00, b0, (f32x4){0.f, 0.f, 0.f, 0.f});
    ac = mfma16(aw01, b1, ac);
    uint2 uu;
    float s0 = masked ? 1e9f : softplus_f(ac[0] + bias0[0]);
    float s1 = masked ? 1e9f : softplus_f(ac[1] + bias0[1]);
    float s2 = masked ? 1e9f : softplus_f(ac[2] + bias0[2]);
    float s3 = masked ? 1e9f : softplus_f(ac[3] + bias0[3]);
    uu.x = pack_bf2_rne(s0, s1); uu.y = pack_bf2_rne(s2, s3);
    *(uint2*)&dt_w[buf][tloc * 68 + dh * 32 + q * 4] = uu;
    ac = mfma16(aw10, b0, (f32x4){0.f, 0.f, 0.f, 0.f});
    ac = mfma16(aw11, b1, ac);
    s0 = masked ? 1e9f : softplus_f(ac[0] + bias1[0]);
    s1 = masked ? 1e9f : softplus_f(ac[1] + bias1[1]);
    s2 = masked ? 1e9f : softplus_f(ac[2] + bias1[2]);
    s3 = masked ? 1e9f : softplus_f(ac[3] + bias1[3]);
    uu.x = pack_bf2_rne(s0, s1); uu.y = pack_bf2_rne(s2, s3);
    *(uint2*)&dt_w[buf][tloc * 68 + dh * 32 + 16 + q * 4] = uu;
  };

  stage(cb, 0);
  dtc(cb, 0);
  __syncthreads();

  for (int win = 0; win < CHT / WIN; ++win) {
    const int curb = win & 1;
    const int t0 = cb + win * WIN;
    if (win < CHT / WIN - 1) { stage(t0 + WIN, curb ^ 1); dtc(t0 + WIN, curb ^ 1); }

    float dtv = bf2f(dt_w[curb][grp]);
    float xv = x_w[curb][grp];
    f32x4 Bv = *(const f32x4*)&b_w[curb][n0];
#pragma unroll 8
    for (int tt = 0; tt < WIN; ++tt) {
      float dtv_n = bf2f(dt_w[curb][(tt + 1) * 68 + grp]);
      float xv_n = x_w[curb][(tt + 1) * 64 + grp];
      f32x4 Bv_n = *(const f32x4*)&b_w[curb][(tt + 1) * 16 + n0];

      bool live = dtv < 1e8f;
      float dtx = live ? dtv * xv : 0.f;
#pragma unroll
      for (int n = 0; n < 4; ++n) {
        float e = __builtin_amdgcn_exp2f(cA[n] * dtv);
        h[n] = fmaf(e, h[n], dtx * Bv[n]);
      }
      S += dtv;
      dtv = dtv_n; xv = xv_n; Bv = Bv_n;
    }
    __syncthreads();
  }

  if (l2 == 0) Ssum[(size_t)(b * NCH + chunk) * 1024 + d] = S;
  short4 hs;
  hs.x = f2bf_rne(h[0]); hs.y = f2bf_rne(h[1]);
  hs.z = f2bf_rne(h[2]); hs.w = f2bf_rne(h[3]);
  *(short4*)(Hio + ((size_t)(b * NCH + chunk) * 1024 + d) * 16 + n0) = hs;
}

// ---------------- combine: prefix over chunks, in-place Hio := h_in ----------------
// grid 512: thread = (b,d,n)
__global__ __launch_bounds__(256) void k_comb(
    const float* __restrict__ al2, const float* __restrict__ Ssum,
    short* __restrict__ Hio) {
  int g = blockIdx.x * 256 + threadIdx.x;
  int b = g >> 14;
  int r = g & 16383;
  int d = r >> 4;
  const float cA = al2[r];
  float H = 0.f;
  for (int c = 0; c < NCH; ++c) {
    size_t base = (size_t)(b * NCH + c) * 1024 + d;
    float s = Ssum[base];
    size_t idx = base * 16 + (r & 15);
    float hf = bf2f(Hio[idx]);
    float e = __builtin_amdgcn_exp2f(cA * s);
    Hio[idx] = f2bf_rne(H);        // h_in for chunk c = H_{c-1}
    H = fmaf(e, H, hf);
  }
}

// ---------------- pass 2: full rescan with h_in, write Y once ----------------
__global__ __launch_bounds__(256) void k_sc2(
    const float* __restrict__ x, const float* __restrict__ BC,
    const short* __restrict__ xp_dt, const short* __restrict__ wdt_bf,
    const float* __restrict__ bdt, const float* __restrict__ al2,
    const float* __restrict__ Dparam, const uint32_t* __restrict__ padbits,
    const short* __restrict__ Hio, float* __restrict__ Y) {
  __shared__ float x_w[2][33 * 64];
  __shared__ short dt_w[2][33 * 68];
  __shared__ float bc_w[2][33 * 32];

  const int tid = threadIdx.x;
  const int w = tid >> 6, l = tid & 63;
  const int cl = l & 15, q = l >> 4, kb = q * 8;
  const int dg = blockIdx.x & 15;
  const int chunk = (blockIdx.x >> 4) & 15;
  const int b = blockIdx.x >> 8;
  const int d0 = dg * 64;
  const int cb = chunk * CHT;
  const int grp = tid >> 2, l2 = tid & 3, n0 = l2 * 4;
  const int d = d0 + grp;
  const int th = w & 1, dh = w >> 1;

  const f32x4 cA = *(const f32x4*)(al2 + (size_t)d * 16 + n0);
  const float Dp = Dparam[d];

  const short* wr0 = wdt_bf + (size_t)(d0 + dh * 32 + cl) * 64 + kb;
  const short* wr1 = wdt_bf + (size_t)(d0 + dh * 32 + 16 + cl) * 64 + kb;
  bf16x8 aw00 = *(const bf16x8*)(wr0);
  bf16x8 aw01 = *(const bf16x8*)(wr0 + 32);
  bf16x8 aw10 = *(const bf16x8*)(wr1);
  bf16x8 aw11 = *(const bf16x8*)(wr1 + 32);
  f32x4 bias0 = *(const f32x4*)(bdt + d0 + dh * 32 + q * 4);
  f32x4 bias1 = *(const f32x4*)(bdt + d0 + dh * 32 + 16 + q * 4);

  float h[4];
  {
    short4 hi4 = *(const short4*)(Hio + ((size_t)(b * NCH + chunk) * 1024 + d) * 16 + n0);
    h[0] = bf2f(hi4.x); h[1] = bf2f(hi4.y); h[2] = bf2f(hi4.z); h[3] = bf2f(hi4.w);
  }

  auto stage = [&](int t0, int buf) {
    const float* xg = x + ((size_t)(b * TLEN + t0)) * DIN + d0;
#pragma unroll
    for (int r = 0; r < 2; ++r) {
      int flat = r * 1024 + w * 256 + l * 4;
      int tt = flat >> 6, cc = flat & 63;
      gl_lds16(xg + (size_t)tt * DIN + cc, &x_w[buf][r * 1024 + w * 256]);
    }
    gl_lds16(BC + ((size_t)(b * TLEN + t0)) * 32 + w * 256 + l * 4, &bc_w[buf][w * 256]);
  };

  auto dtc = [&](int t0, int buf) {
    uint32_t mw = padbits[b * 64 + (t0 >> 5)];
    int tloc = th * 16 + cl;
    bool masked = (mw >> tloc) & 1;
    const short* ag = xp_dt + (size_t)(b * TLEN + t0 + tloc) * 64 + kb;
    bf16x8 b0 = *(const bf16x8*)(ag);
    bf16x8 b1 = *(const bf16x8*)(ag + 32);
    f32x4 ac = mfma16(aw00, b0, (f32x4){0.f, 0.f, 0.f, 0.f});
    ac = mfma16(aw01, b1, ac);
    uint2 uu;
    float s0 = masked ? 1e9f : softplus_f(ac[0] + bias0[0]);
    float s1 = masked ? 1e9f : softplus_f(ac[1] + bias0[1]);
    float s2 = masked ? 1e9f : softplus_f(ac[2] + bias0[2]);
    float s3 = masked ? 1e9f : softplus_f(ac[3] + bias0[3]);
    uu.x = pack_bf2_rne(s0, s1); uu.y = pack_bf2_rne(s2, s3);
    *(uint2*)&dt_w[buf][tloc * 68 + dh * 32 + q * 4] = uu;
    ac = mfma16(aw10, b0, (f32x4){0.f, 0.f, 0.f, 0.f});
    ac = mfma16(aw11, b1, ac);
    s0 = masked ? 1e9f : softplus_f(ac[0] + bias1[0]);
    s1 = masked ? 1e9f : softplus_f(ac[1] + bias1[1]);
    s2 = masked ? 1e9f : softplus_f(ac[2] + bias1[2]);
    s3 = masked ? 1e9f : softplus_f(ac[3] + bias1[3]);
    uu.x = pack_bf2_rne(s0, s1); uu.y = pack_bf2_rne(s2, s3);
    *(uint2*)&dt_w[buf][tloc * 68 + dh * 32 + 16 + q * 4] = uu;
  };

  stage(cb, 0);
  dtc(cb, 0);
  __syncthreads();

  for (int win = 0; win < CHT / WIN; ++win) {
    const int curb = win & 1;
    const int t0 = cb + win * WIN;
    if (win < CHT / WIN - 1) { stage(t0 + WIN, curb ^ 1); dtc(t0 + WIN, curb ^ 1); }

    float* ybase = Y + ((size_t)(b * TLEN + t0)) * DIN + d;
    float dtv = bf2f(dt_w[curb][grp]);
    float xv = x_w[curb][grp];
    f32x4 Bv = *(const f32x4*)&bc_w[curb][n0];
    f32x4 Cv = *(const f32x4*)&bc_w[curb][16 + n0];
#pragma unroll 8
    for (int tt = 0; tt < WIN; ++tt) {
      float dtv_n = bf2f(dt_w[curb][(tt + 1) * 68 + grp]);
      float xv_n = x_w[curb][(tt + 1) * 64 + grp];
      f32x4 Bv_n = *(const f32x4*)&bc_w[curb][(tt + 1) * 32 + n0];
      f32x4 Cv_n = *(const f32x4*)&bc_w[curb][(tt + 1) * 32 + 16 + n0];

      bool live = dtv < 1e8f;
      float dtx = live ? dtv * xv : 0.f;
#pragma unroll
      for (int n = 0; n < 4; ++n) {
        float e = __builtin_amdgcn_exp2f(cA[n] * dtv);
        h[n] = fmaf(e, h[n], dtx * Bv[n]);
      }
      float p = h[0] * Cv[0];
      p = fmaf(h[1], Cv[1], p);
      p = fmaf(h[2], Cv[2], p);
      p = fmaf(h[3], Cv[3], p);
      p = dpp_add<0xB1>(p);
      p = dpp_add<0x4E>(p);
      float yv = live ? fmaf(Dp, xv, p) : 0.f;
      if (l2 == 0) ybase[(size_t)tt * DIN] = yv;

      dtv = dtv_n; xv = xv_n; Bv = Bv_n; Cv = Cv_n;
    }
    __syncthreads();
  }
}

extern "C" void kernel_launch(void* const* d_in, const int* in_sizes, int n_in,
                              void* d_out, int out_size, void* d_ws, size_t ws_size,
                              hipStream_t stream) {
  const float* x = (const float*)d_in[0];
  const unsigned char* pad = (const unsigned char*)d_in[1];
  const float* Wxp = (const float*)d_in[2];
  const float* Wdt = (const float*)d_in[3];
  const float* bdt = (const float*)d_in[4];
  const float* logA = (const float*)d_in[5];
  const float* Dpar = (const float*)d_in[6];
  float* Y = (float*)d_out;

  char* ws = (char*)d_ws;
  short* wxp_bf     = (short*)(ws);                 // 196608
  short* wdt_bf     = (short*)(ws + 196608);        // 131072
  float* al2        = (float*)(ws + 327680);        // 65536
  short* xp_dt      = (short*)(ws + 393216);        // 2097152
  float* BC         = (float*)(ws + 2490368);       // 2097152
  float* Ssum       = (float*)(ws + 4587520);       // 524288
  short* Hio        = (short*)(ws + 5111808);       // 4194304 (bf16 h_fin -> h_in)
  uint32_t* padbits = (uint32_t*)(ws + 9306112);    // 2048  (total ~9.31 MB)

  hipLaunchKernelGGL(k_prep, dim3(384), dim3(256), 0, stream,
                     Wxp, Wdt, logA, pad, wxp_bf, wdt_bf, al2, padbits);
  hipLaunchKernelGGL(k_proj, dim3(512), dim3(256), 0, stream,
                     x, wxp_bf, xp_dt, BC);
  hipLaunchKernelGGL(k_sc1, dim3(2048), dim3(256), 0, stream,
                     x, BC, xp_dt, wdt_bf, bdt, al2, padbits, Ssum, Hio);
  hipLaunchKernelGGL(k_comb, dim3(512), dim3(256), 0, stream,
                     al2, Ssum, Hio);
  hipLaunchKernelGGL(k_sc2, dim3(2048), dim3(256), 0, stream,
                     x, BC, xp_dt, wdt_bf, bdt, al2, Dpar, padbits, Hio, Y);
}